// Round 9
// baseline (284.600 us; speedup 1.0000x reference)
//
#include <hip/hip_runtime.h>
#include <hip/hip_bf16.h>

#define NFEAT 128
#define BCAP 8192     // bucket capacity (and bin-pass chunk size), edges
#define BSHIFT 8      // 256 nodes per bucket
#define TPAD 136      // padded LDS tile row stride (shorts), 16B-aligned

typedef __attribute__((ext_vector_type(8))) short short8;
typedef __attribute__((ext_vector_type(4))) float float4v;

__device__ inline short f32_bf16(float f) {
  unsigned u = __builtin_bit_cast(unsigned, f);
  unsigned r = (u + 0x7fffu + ((u >> 16) & 1u)) >> 16;
  return (short)r;
}
__device__ inline float bf16_f32(unsigned short s) {
  return __builtin_bit_cast(float, (unsigned)s << 16);
}

// ---------------------------------------------------------------------------
// Repack W (fp32, KxCOLS row-major) into B-fragment order for
// mfma_f32_16x16x32_bf16: frag f = ((t*4 + c)*64 + lane):
//   Wf[f*8 + j] = bf16( W[(c*32 + (lane>>4)*8 + j)*COLS + t*16 + (lane&15)] )
// ---------------------------------------------------------------------------
__device__ inline void repack_one(const float* __restrict__ W,
                                  short* __restrict__ Wf, int COLS) {
  int nfrag = (COLS / 16) * 4 * 64;
  for (int f = threadIdx.x; f < nfrag; f += 256) {
    int lane = f & 63, c = (f >> 6) & 3, t = f >> 8;
    int k0 = c * 32 + (lane >> 4) * 8;
    int n = t * 16 + (lane & 15);
    short8 v;
#pragma unroll
    for (int j = 0; j < 8; j++) v[j] = f32_bf16(W[(size_t)(k0 + j) * COLS + n]);
    *(short8*)&Wf[(size_t)f * 8] = v;
  }
}
__global__ __launch_bounds__(256) void repack_w_kernel(
    const float* __restrict__ W1, short* __restrict__ W1f,
    const float* __restrict__ W2, short* __restrict__ W2f) {
  if (blockIdx.x == 0) repack_one(W1, W1f, 128);
  else repack_one(W2, W2f, 64);
}

// ---------------------------------------------------------------------------
// K_pre: bin (low blockIdx -> scheduled first) fused with x->bf16 convert.
// ---------------------------------------------------------------------------
__global__ __launch_bounds__(256) void k_pre(
    const int* __restrict__ src, const int* __restrict__ dst,
    int* __restrict__ bucket_cnt, int* __restrict__ bucket_arr,
    int E, int NB, int nbin,
    const float* __restrict__ x, short* __restrict__ xb, int total8,
    int nconv) {
  __shared__ int smem[1024];
  const int tid = threadIdx.x;
  if ((int)blockIdx.x < nbin) {
    // ---- bin role ----
    int* hist = smem;
    int* cur = smem + 512;
    const int base = blockIdx.x * BCAP;
    const int end = min(E, base + BCAP);
    for (int i = tid; i < NB; i += 256) hist[i] = 0;
    __syncthreads();
    for (int e = base + tid; e < end; e += 256)
      atomicAdd(&hist[dst[e] >> BSHIFT], 1);
    __syncthreads();
    for (int b = tid; b < NB; b += 256) {
      int c = hist[b];
      cur[b] = c ? (b * BCAP + atomicAdd(&bucket_cnt[b], c)) : 0;
    }
    __syncthreads();
    for (int e = base + tid; e < end; e += 256) {
      int d = dst[e];
      int b = d >> BSHIFT;
      int pos = atomicAdd(&cur[b], 1);
      bucket_arr[pos] = (src[e] << BSHIFT) | (d & 255);
    }
  } else {
    // ---- convert role: 8 floats -> 8 bf16 per thread-iter ----
    const int bid = blockIdx.x - nbin;
    for (int i = bid * 256 + tid; i < total8; i += nconv * 256) {
      float4 a = ((const float4*)x)[2 * i];
      float4 b = ((const float4*)x)[2 * i + 1];
      short8 v;
      v[0] = f32_bf16(a.x); v[1] = f32_bf16(a.y);
      v[2] = f32_bf16(a.z); v[3] = f32_bf16(a.w);
      v[4] = f32_bf16(b.x); v[5] = f32_bf16(b.y);
      v[6] = f32_bf16(b.z); v[7] = f32_bf16(b.w);
      ((short8*)xb)[i] = v;
    }
  }
}

// Tiny exclusive scan over NB bucket counts (NB <= 512), plus offsets[N]=E.
__global__ __launch_bounds__(512) void bucket_scan_kernel(
    const int* __restrict__ bucket_cnt, int* __restrict__ bucket_base,
    int* __restrict__ offsets, int NB, int N, int E) {
  __shared__ int sh[512];
  const int t = threadIdx.x;
  int v = (t < NB) ? bucket_cnt[t] : 0;
  sh[t] = v;
  __syncthreads();
  for (int off = 1; off < 512; off <<= 1) {
    int o = (t >= off) ? sh[t - off] : 0;
    __syncthreads();
    sh[t] += o;
    __syncthreads();
  }
  if (t < NB) bucket_base[t] = sh[t] - v;  // exclusive
  if (t == 0) offsets[N] = E;
}

// ---------------------------------------------------------------------------
// One block per bucket: LDS counting sort -> coalesced csr_src + offsets.
// ---------------------------------------------------------------------------
__global__ __launch_bounds__(256) void csr_build_kernel(
    const int* __restrict__ bucket_arr, const int* __restrict__ bucket_cnt,
    const int* __restrict__ bucket_base, int* __restrict__ offsets,
    int* __restrict__ csr_src, int N) {
  __shared__ int eds[BCAP];
  __shared__ int stage[BCAP];
  __shared__ int cnt256[256], pfx[256], cur[256];
  const int b = blockIdx.x;
  const int tid = threadIdx.x;
  const int cnt = bucket_cnt[b];
  const int gbase = bucket_base[b];
  const int node0 = b << BSHIFT;
  const int nnodes = min(256, N - node0);

  for (int i = tid; i < cnt; i += 256) eds[i] = bucket_arr[b * BCAP + i];
  cnt256[tid] = 0;
  __syncthreads();
  for (int i = tid; i < cnt; i += 256) atomicAdd(&cnt256[eds[i] & 255], 1);
  __syncthreads();
  int v = cnt256[tid];
  pfx[tid] = v;
  __syncthreads();
  for (int off = 1; off < 256; off <<= 1) {
    int o = (tid >= off) ? pfx[tid - off] : 0;
    __syncthreads();
    pfx[tid] += o;
    __syncthreads();
  }
  int excl = pfx[tid] - v;
  cur[tid] = excl;
  if (tid < nnodes) offsets[node0 + tid] = gbase + excl;
  __syncthreads();
  for (int i = tid; i < cnt; i += 256) {
    int e = eds[i];
    int pos = atomicAdd(&cur[e & 255], 1);
    stage[pos] = e >> BSHIFT;
  }
  __syncthreads();
  for (int i = tid; i < cnt; i += 256) csr_src[gbase + i] = stage[i];
}

// ---------------------------------------------------------------------------
// agg1: aggX[n] = sum over edges into n of xb[src]  (bf16 out, fp32 acc).
// One wave per node, 8-way unrolled gather.
// ---------------------------------------------------------------------------
__global__ __launch_bounds__(256) void agg1_kernel(
    const short* __restrict__ Xb, const int* __restrict__ csr_src,
    const int* __restrict__ offsets, short* __restrict__ aggX, int N) {
  const int node = (blockIdx.x * 256 + threadIdx.x) >> 6;
  const int lane = threadIdx.x & 63;
  if (node >= N) return;
  const int start = offsets[node];
  const int end = offsets[node + 1];
  float a0 = 0.f, a1 = 0.f;
  for (int base = start; base < end; base += 64) {
    int my = (base + lane < end) ? csr_src[base + lane] : 0;
    int mcnt = min(64, end - base);
    int j = 0;
    for (; j + 8 <= mcnt; j += 8) {
      unsigned v[8];
#pragma unroll
      for (int k = 0; k < 8; k++) {
        int s = __shfl(my, j + k);
        v[k] = *(const unsigned*)&Xb[(size_t)s * 128 + 2 * lane];
      }
#pragma unroll
      for (int k = 0; k < 8; k++) {
        a0 += __builtin_bit_cast(float, v[k] << 16);
        a1 += __builtin_bit_cast(float, v[k] & 0xffff0000u);
      }
    }
    for (; j < mcnt; j++) {
      int s = __shfl(my, j);
      unsigned v = *(const unsigned*)&Xb[(size_t)s * 128 + 2 * lane];
      a0 += __builtin_bit_cast(float, v << 16);
      a1 += __builtin_bit_cast(float, v & 0xffff0000u);
    }
  }
  unsigned outv = (unsigned)(unsigned short)f32_bf16(a0) |
                  ((unsigned)(unsigned short)f32_bf16(a1) << 16);
  *(unsigned*)&aggX[(size_t)node * 128 + 2 * lane] = outv;
}

// ---------------------------------------------------------------------------
// Fused MLP: y2 = relu(aggX @ W1 + b1) @ W2, per 64-row tile, h never
// leaves the CU. LDS: W1 frags 32KB + W2 frags 16KB + padded tile 17KB.
// ---------------------------------------------------------------------------
__global__ __launch_bounds__(256) void mlp_fused_kernel(
    const short* __restrict__ aggX, const short* __restrict__ w1f,
    const short* __restrict__ w2f, const float* __restrict__ b1,
    short* __restrict__ y2, int nrows, int ntiles) {
  __shared__ __align__(16) short w1s[128 * 128];
  __shared__ __align__(16) short w2s[64 * 128];
  __shared__ __align__(16) short tile[64 * TPAD];

  const int tid = threadIdx.x;
  for (int i = tid; i < 128 * 16; i += 256) ((int4*)w1s)[i] = ((const int4*)w1f)[i];
  for (int i = tid; i < 64 * 16; i += 256) ((int4*)w2s)[i] = ((const int4*)w2f)[i];

  const int wave = tid >> 6;
  const int lane = tid & 63;
  const int m = lane & 15;
  const int q = lane >> 4;

  float bias1[8];
#pragma unroll
  for (int t = 0; t < 8; t++) bias1[t] = b1[t * 16 + m];
  __syncthreads();

  const short8* w1frag = (const short8*)w1s;
  const short8* w2frag = (const short8*)w2s;

  for (int ti = blockIdx.x; ti < ntiles; ti += gridDim.x) {
    const int row0 = ti * 64;
    const int rowA = row0 + wave * 16 + m;

    // ---- GEMM 1: aggX(64x128) @ W1(128x128) ----
    float4v acc[8];
#pragma unroll
    for (int t = 0; t < 8; t++) acc[t] = (float4v){0.f, 0.f, 0.f, 0.f};
#pragma unroll
    for (int c = 0; c < 4; c++) {
      short8 a = (short8){0, 0, 0, 0, 0, 0, 0, 0};
      if (rowA < nrows)
        a = *(const short8*)&aggX[(size_t)rowA * 128 + c * 32 + q * 8];
#pragma unroll
      for (int t = 0; t < 8; t++)
        acc[t] = __builtin_amdgcn_mfma_f32_16x16x32_bf16(
            a, w1frag[(t * 4 + c) * 64 + lane], acc[t], 0, 0, 0);
    }
    // epilogue: +b1, relu, store bf16 into padded LDS tile [row][col]
#pragma unroll
    for (int t = 0; t < 8; t++) {
#pragma unroll
      for (int r = 0; r < 4; r++) {
        float v = fmaxf(acc[t][r] + bias1[t], 0.f);
        tile[(wave * 16 + q * 4 + r) * TPAD + t * 16 + m] = f32_bf16(v);
      }
    }
    __syncthreads();

    // ---- GEMM 2: h(64x128) @ W2(128x64) ----
    float4v acc2[4];
#pragma unroll
    for (int t = 0; t < 4; t++) acc2[t] = (float4v){0.f, 0.f, 0.f, 0.f};
#pragma unroll
    for (int c = 0; c < 4; c++) {
      short8 a2 = *(const short8*)&tile[(wave * 16 + m) * TPAD + c * 32 + q * 8];
#pragma unroll
      for (int t = 0; t < 4; t++)
        acc2[t] = __builtin_amdgcn_mfma_f32_16x16x32_bf16(
            a2, w2frag[(t * 4 + c) * 64 + lane], acc2[t], 0, 0, 0);
    }
    const int rbase = row0 + wave * 16 + q * 4;
#pragma unroll
    for (int t = 0; t < 4; t++) {
#pragma unroll
      for (int r = 0; r < 4; r++) {
        int rr = rbase + r;
        if (rr < nrows) y2[(size_t)rr * 64 + t * 16 + m] = f32_bf16(acc2[t][r]);
      }
    }
    __syncthreads();  // tile reused next iteration
  }
}

// ---------------------------------------------------------------------------
// agg2: out[n] = b2 + sum over edges into n of y2[src]  (fp32 out).
// ---------------------------------------------------------------------------
__global__ __launch_bounds__(256) void agg2_kernel(
    const short* __restrict__ Y, const int* __restrict__ csr_src,
    const int* __restrict__ offsets, const float* __restrict__ bias,
    float* __restrict__ out, int N) {
  const int node = (blockIdx.x * 256 + threadIdx.x) >> 6;
  const int lane = threadIdx.x & 63;
  if (node >= N) return;
  const int start = offsets[node];
  const int end = offsets[node + 1];
  float acc = bias[lane];
  for (int base = start; base < end; base += 64) {
    int my = (base + lane < end) ? csr_src[base + lane] : 0;
    int mcnt = min(64, end - base);
    int j = 0;
    for (; j + 8 <= mcnt; j += 8) {
      unsigned short w[8];
#pragma unroll
      for (int k = 0; k < 8; k++) {
        int s = __shfl(my, j + k);
        w[k] = *(const unsigned short*)&Y[(size_t)s * 64 + lane];
      }
#pragma unroll
      for (int k = 0; k < 8; k++) acc += bf16_f32(w[k]);
    }
    for (; j < mcnt; j++) {
      int s = __shfl(my, j);
      acc += bf16_f32(*(const unsigned short*)&Y[(size_t)s * 64 + lane]);
    }
  }
  out[(size_t)node * 64 + lane] = acc;
}

extern "C" void kernel_launch(void* const* d_in, const int* in_sizes, int n_in,
                              void* d_out, int out_size, void* d_ws, size_t ws_size,
                              hipStream_t stream) {
  const float* x  = (const float*)d_in[0];
  const int* src  = (const int*)d_in[1];
  const int* dst  = (const int*)d_in[2];
  const float* W1 = (const float*)d_in[3];
  const float* b1 = (const float*)d_in[4];
  const float* W2 = (const float*)d_in[5];
  const float* b2 = (const float*)d_in[6];
  float* out = (float*)d_out;

  const int N = in_sizes[0] / NFEAT;   // 100000
  const int E = in_sizes[1];           // 1600000
  const int NB = (N + 255) >> BSHIFT;  // 391 buckets

  // workspace layout
  short* xb   = (short*)d_ws;                      // N*128 bf16
  short* aggX = xb + (size_t)N * 128;              // N*128 bf16
  short* y2   = aggX + (size_t)N * 128;            // N*64 bf16
  short* w1f  = y2 + (size_t)N * 64;               // 128*128 bf16
  short* w2f  = w1f + 128 * 128;                   // 128*64 bf16
  int* bucket_cnt  = (int*)(((uintptr_t)(w2f + 128 * 64) + 15) & ~(uintptr_t)15);
  int* bucket_base = bucket_cnt + 512;             // 512
  int* offsets     = bucket_base + 512;            // N+1
  int* csr_src     = offsets + N + 1;              // E
  int* bucket_arr  = csr_src + E;                  // NB*BCAP

  const int agg_blocks = (N * 64 + 255) / 256;
  const int bin_blocks = (E + BCAP - 1) / BCAP;
  const int conv_blocks = 1024;
  const int total8 = N * 128 / 8;
  const int ntiles = (N + 63) / 64;

  // ---- weight repack ----
  repack_w_kernel<<<2, 256, 0, stream>>>(W1, w1f, W2, w2f);
  hipMemsetAsync(bucket_cnt, 0, 512 * sizeof(int), stream);

  // ---- K_pre: bin (first) + x->bf16 convert ----
  k_pre<<<bin_blocks + conv_blocks, 256, 0, stream>>>(
      src, dst, bucket_cnt, bucket_arr, E, NB, bin_blocks,
      x, xb, total8, conv_blocks);

  // ---- CSR finalize ----
  bucket_scan_kernel<<<1, 512, 0, stream>>>(bucket_cnt, bucket_base, offsets,
                                            NB, N, E);
  csr_build_kernel<<<NB, 256, 0, stream>>>(bucket_arr, bucket_cnt, bucket_base,
                                           offsets, csr_src, N);

  // ---- aggregate x, then fused MLP, then aggregate y2 ----
  agg1_kernel<<<agg_blocks, 256, 0, stream>>>(xb, csr_src, offsets, aggX, N);
  mlp_fused_kernel<<<512, 256, 0, stream>>>(aggX, w1f, w2f, b1, y2, N, ntiles);
  agg2_kernel<<<agg_blocks, 256, 0, stream>>>(y2, csr_src, offsets, b2, out, N);
}